// Round 9
// baseline (775.016 us; speedup 1.0000x reference)
//
#include <hip/hip_runtime.h>
#include <hip/hip_bf16.h>

typedef __attribute__((ext_vector_type(8))) short bf16x8;
typedef __attribute__((ext_vector_type(4))) float f32x4;

#define GLD16(g, s) __builtin_amdgcn_global_load_lds( \
    (const __attribute__((address_space(1))) void*)(g), \
    (__attribute__((address_space(3))) void*)(s), 16, 0, 0)

#define SBAR() __builtin_amdgcn_sched_barrier(0)
#define BARRIER() __builtin_amdgcn_s_barrier()
#define WAIT_LGKM0() do { asm volatile("s_waitcnt lgkmcnt(0)" ::: "memory"); SBAR(); } while (0)
#define WAIT_VM0() do { asm volatile("s_waitcnt vmcnt(0)" ::: "memory"); SBAR(); } while (0)

static constexpr int kB  = 128;
static constexpr int kC  = 1280;
static constexpr int kHW = 256;

// TLP-oriented GEMM: C(M,N) = A(M,K)*Bt(N,K)^T.
// BM=BN=128, BK=32; 256 thr = 4 waves (2M x 2N), wave tile 64x64 (acc 4x4).
// 2 LDS slots x 16KB = 32KB total -> 4 blocks/CU (16 waves) with VGPR<=128.
// BK=32 rows are 64B: fragment reads are naturally bank-conflict-free and
// need NO swizzle; ds_read addrs are base+immediate. One barrier + one
// vmcnt(0) per K-tile; stalls hidden by 3 co-resident blocks (m97/m114 TLP).
// OUT_MODE: 0=bf16 rowmajor, 1=f32 rowmajor, 2=bf16 conv, 3=f32 conv alpha*()+resid
// BIAS_MODE: 0=none, 1=bias[col], 2=bias[row]
// ORDER: 0 = m-fastest (B operand large), 1 = n-fastest (A operand large)
template<int OUT_MODE, int BIAS_MODE, int ORDER>
__global__ __launch_bounds__(256, 4) void gemm_u(
    const __hip_bfloat16* __restrict__ A,
    const __hip_bfloat16* __restrict__ Bt,
    void* __restrict__ outp,
    const float* __restrict__ bias,
    const float* __restrict__ resid,
    const float* __restrict__ alphap,
    int M, int N, int K,
    int ldA, int ldB, long sA, long sB, long sC, int ldC)
{
    __shared__ char smem[32768];     // 2 slots x (A 8KB + B 8KB)
    const int t = threadIdx.x;
    const int w = t >> 6, l = t & 63;
    const int q = l >> 4, r16 = l & 15;
    const int wr = w >> 1, wc = w & 1;   // 2M x 2N waves
    const int z = blockIdx.z;
    const int nbm = M >> 7, nbn = N >> 7;
    const int nwg = nbm * nbn;
    int f = blockIdx.x;
    {   // bijective XCD swizzle (m204)
        const int q8 = nwg >> 3, r8 = nwg & 7;
        const int xcd = f & 7, rank = f >> 3;
        f = (xcd < r8 ? xcd * (q8 + 1) : r8 * (q8 + 1) + (xcd - r8) * q8) + rank;
    }
    long m0, n0;
    if (ORDER == 0) { m0 = (long)(f % nbm) << 7; n0 = (long)(f / nbm) << 7; }
    else            { n0 = (long)(f % nbn) << 7; m0 = (long)(f / nbn) << 7; }
    const char* Azb = (const char*)(A + (long)z * sA);
    const char* Bzb = (const char*)(Bt + (long)z * sB);

    // ---- staging addresses (linear, no swizzle; advance +64B per K-tile) ----
    const char* pa[2];
    const char* pb[2];
    int ldsd[2];
    #pragma unroll
    for (int i = 0; i < 2; ++i) {
        const int d = i * 4096 + t * 16;
        const int row = d >> 6;              // 64B per row (BK*2)
        const int cb = d & 63;
        pa[i] = Azb + ((m0 + row) * (long)ldA) * 2 + cb;
        pb[i] = Bzb + ((n0 + row) * (long)ldB) * 2 + cb;
        ldsd[i] = d;
    }
    auto stage4 = [&](char* base) {
        GLD16(pa[0], base + ldsd[0]);
        GLD16(pa[1], base + ldsd[1]);
        GLD16(pb[0], base + 8192 + ldsd[0]);
        GLD16(pb[1], base + 8192 + ldsd[1]);
        pa[0] += 64; pa[1] += 64; pb[0] += 64; pb[1] += 64;
    };

    // ---- LDS read offsets (base + mi*1024 immediates; conflict-free) ----
    const int aoff = (wr * 64 + r16) * 64 + q * 16;
    const int boff = 8192 + (wc * 64 + r16) * 64 + q * 16;

    f32x4 acc[4][4] = {};
    const int nK = K >> 5;

    stage4(smem);                      // tile 0 -> slot 0

    for (int tk = 0; tk < nK; ++tk) {
        char* sb = smem + (tk & 1) * 16384;
        char* nb = smem + ((tk & 1) ^ 1) * 16384;

        WAIT_VM0();                    // own tile-tk loads landed
        BARRIER();                     // everyone's landed; nb's readers retired
        SBAR();

        bf16x8 a[4], b[4];
        #pragma unroll
        for (int ni = 0; ni < 4; ++ni)
            b[ni] = *reinterpret_cast<const bf16x8*>(sb + boff + ni * 1024);
        #pragma unroll
        for (int mi = 0; mi < 4; ++mi)
            a[mi] = *reinterpret_cast<const bf16x8*>(sb + aoff + mi * 1024);
        if (tk + 1 < nK) stage4(nb);   // issue next tile while reads in flight
        WAIT_LGKM0();

        __builtin_amdgcn_s_setprio(1);
        #pragma unroll
        for (int mi = 0; mi < 4; ++mi)
            #pragma unroll
            for (int ni = 0; ni < 4; ++ni)
                acc[mi][ni] = __builtin_amdgcn_mfma_f32_16x16x32_bf16(
                    a[mi], b[ni], acc[mi][ni], 0, 0, 0);
        __builtin_amdgcn_s_setprio(0);
        SBAR();
    }

    const float alpha = (OUT_MODE == 3) ? alphap[0] : 0.0f;
    #pragma unroll
    for (int mi = 0; mi < 4; ++mi) {
        #pragma unroll
        for (int ni = 0; ni < 4; ++ni) {
            #pragma unroll
            for (int r = 0; r < 4; ++r) {
                const long row = m0 + wr * 64 + mi * 16 + q * 4 + r;
                const long col = n0 + wc * 64 + ni * 16 + r16;
                float vv = acc[mi][ni][r];
                if (BIAS_MODE == 1) vv += bias[col];
                if (BIAS_MODE == 2) vv += bias[row];
                if (OUT_MODE == 0) {
                    ((__hip_bfloat16*)outp)[(long)z * sC + row * ldC + col] = __float2bfloat16(vv);
                } else if (OUT_MODE == 1) {
                    ((float*)outp)[(long)z * sC + row * ldC + col] = vv;
                } else if (OUT_MODE == 2) {
                    const long addr = (col >> 8) * (long)(kC * kHW) + row * kHW + (col & 255);
                    ((__hip_bfloat16*)outp)[addr] = __float2bfloat16(vv);
                } else {
                    const long addr = (col >> 8) * (long)(kC * kHW) + row * kHW + (col & 255);
                    ((float*)outp)[addr] = alpha * vv + resid[addr];
                }
            }
        }
    }
}

// x (B, C, HW) f32  ->  xT (B*HW, C) bf16
__global__ __launch_bounds__(256) void transpose_x(
    const float* __restrict__ x, __hip_bfloat16* __restrict__ xT)
{
    __shared__ float tile[64][65];
    const int b = blockIdx.z;
    const int c0 = blockIdx.x * 64;
    const int p0 = blockIdx.y * 64;
    const int tj = threadIdx.x & 63;
    const int ti = threadIdx.x >> 6;
    const float* xb = x + ((long)b * kC + c0) * kHW + p0;
    #pragma unroll
    for (int i = 0; i < 16; ++i) {
        const int c = i * 4 + ti;
        tile[c][tj] = xb[(long)c * kHW + tj];
    }
    __syncthreads();
    __hip_bfloat16* o = xT + ((long)(b * kHW + p0)) * kC + c0;
    #pragma unroll
    for (int i = 0; i < 16; ++i) {
        const int p = i * 4 + ti;
        o[(long)p * kC + tj] = __float2bfloat16(tile[tj][p]);
    }
}

__global__ __launch_bounds__(256) void convert_f32_bf16(
    const float* __restrict__ s, __hip_bfloat16* __restrict__ d)
{
    const int i = (blockIdx.x * 256 + threadIdx.x) * 4;
    const float4 f = *reinterpret_cast<const float4*>(s + i);
    d[i + 0] = __float2bfloat16(f.x);
    d[i + 1] = __float2bfloat16(f.y);
    d[i + 2] = __float2bfloat16(f.z);
    d[i + 3] = __float2bfloat16(f.w);
}

__global__ __launch_bounds__(256) void concat_bias(
    const float* __restrict__ bk, const float* __restrict__ bq, float* __restrict__ bc)
{
    const int i = blockIdx.x * 256 + threadIdx.x;  // grid 10*256 = 2560
    bc[i] = (i < 1280) ? bk[i] : bq[i - 1280];
}

// softmax over BATCH axis: scores (B,256,256) f32 -> attn bf16
__global__ __launch_bounds__(256) void softmax_batch(
    const float* __restrict__ scores, __hip_bfloat16* __restrict__ attn)
{
    const int pos = blockIdx.x * 256 + threadIdx.x;
    float m = -3.0e38f, s = 0.0f;
    for (int b = 0; b < kB; ++b) {
        const float v = scores[(long)b * 65536 + pos];
        const float mn = fmaxf(m, v);
        s = s * __expf(m - mn) + __expf(v - mn);
        m = mn;
    }
    const float rinv = 1.0f / s;
    for (int b = 0; b < kB; ++b) {
        const float v = scores[(long)b * 65536 + pos];
        attn[(long)b * 65536 + pos] = __float2bfloat16(__expf(v - m) * rinv);
    }
}

extern "C" void kernel_launch(void* const* d_in, const int* in_sizes, int n_in,
                              void* d_out, int out_size, void* d_ws, size_t ws_size,
                              hipStream_t stream)
{
    const float* x  = (const float*)d_in[0];
    const float* Wk = (const float*)d_in[1];
    const float* bk = (const float*)d_in[2];
    const float* Wq = (const float*)d_in[3];
    const float* bq = (const float*)d_in[4];
    const float* Wv = (const float*)d_in[5];
    const float* bv = (const float*)d_in[6];
    const float* Wr = (const float*)d_in[7];
    const float* br = (const float*)d_in[8];
    const float* al = (const float*)d_in[9];

    char* ws = (char*)d_ws;
    __hip_bfloat16* xT   = (__hip_bfloat16*)(ws);               // 83.9MB; dead after V GEMM
    float*          sc   = (float*)(ws);                        // aliases xT (33.5MB)
    __hip_bfloat16* kqT  = (__hip_bfloat16*)(ws + 83886080L);   // (32768,2560) 167.8MB
    __hip_bfloat16* attn = (__hip_bfloat16*)(ws + 83886080L);   // aliases kqT (16.8MB)
    __hip_bfloat16* att2 = (__hip_bfloat16*)(ws + 100663296L);  // aliases kqT tail (83.9MB)
    __hip_bfloat16* vv   = (__hip_bfloat16*)(ws + 251658240L);  // 83.9MB
    __hip_bfloat16* Wcatb= (__hip_bfloat16*)(ws + 335544320L);  // (2560,1280)
    __hip_bfloat16* Wvb  = Wcatb + 2560 * 1280;
    __hip_bfloat16* Wrb  = Wvb + 1280 * 1280;
    float*          bcat = (float*)(ws + 348651520L);           // 2560 f32

    convert_f32_bf16<<<1600, 256, 0, stream>>>(Wk, Wcatb);
    convert_f32_bf16<<<1600, 256, 0, stream>>>(Wq, Wcatb + 1638400);
    convert_f32_bf16<<<1600, 256, 0, stream>>>(Wv, Wvb);
    convert_f32_bf16<<<1600, 256, 0, stream>>>(Wr, Wrb);
    concat_bias<<<10, 256, 0, stream>>>(bk, bq, bcat);
    transpose_x<<<dim3(20, 4, 128), 256, 0, stream>>>(x, xT);

    // fused K|Q: kqT (32768, 2560) = xT * Wcat^T + bcat[col]; A large -> ORDER=1
    gemm_u<0, 1, 1><<<dim3(5120, 1, 1), 256, 0, stream>>>(xT, Wcatb, kqT, bcat, nullptr, nullptr,
        32768, 2560, 1280, 1280, 1280, 0, 0, 0, 2560);
    // v (B,C,HW) = Wv * xT^T + bv[row];  B large -> ORDER=0
    gemm_u<2, 2, 0><<<dim3(2560, 1, 1), 256, 0, stream>>>(Wvb, xT, vv, bv, nullptr, nullptr,
        1280, 32768, 1280, 1280, 1280, 0, 0, 0, 0);
    // scores (B,256,256) f32 = kT[b] * qT[b]^T  (now 4 blocks per batch = 512 blocks)
    gemm_u<1, 0, 0><<<dim3(4, 1, 128), 256, 0, stream>>>(kqT, kqT + 1280, sc, nullptr, nullptr, nullptr,
        256, 256, 1280, 2560, 2560, 655360, 655360, 65536, 256);
    softmax_batch<<<256, 256, 0, stream>>>(sc, attn);
    // att2 (B,256,1280) = attn[b] * v[b]^T
    gemm_u<0, 0, 0><<<dim3(20, 1, 128), 256, 0, stream>>>(attn, vv, att2, nullptr, nullptr, nullptr,
        256, 1280, 256, 256, 256, 65536, 327680, 327680, 1280);
    // out f32 (B,C,HW) = alpha*(Wr*att2^T + br[row]) + x;  B large -> ORDER=0
    gemm_u<3, 2, 0><<<dim3(2560, 1, 1), 256, 0, stream>>>(Wrb, att2, d_out, br, x, al,
        1280, 32768, 1280, 1280, 1280, 0, 0, 0, 0);
}

// Round 10
// 546.394 us; speedup vs baseline: 1.4184x; 1.4184x over previous
//
#include <hip/hip_runtime.h>
#include <hip/hip_bf16.h>

typedef __attribute__((ext_vector_type(8))) short bf16x8;
typedef __attribute__((ext_vector_type(4))) float f32x4;

#define GLD16(g, s) __builtin_amdgcn_global_load_lds( \
    (const __attribute__((address_space(1))) void*)(g), \
    (__attribute__((address_space(3))) void*)(s), 16, 0, 0)

#define SBAR() __builtin_amdgcn_sched_barrier(0)
#define WAIT_LGKM(n) do { asm volatile("s_waitcnt lgkmcnt(" #n ")" ::: "memory"); SBAR(); } while (0)

static constexpr int kB  = 128;
static constexpr int kC  = 1280;
static constexpr int kHW = 256;

__device__ __forceinline__ float bf2f(unsigned short u) {
    return __uint_as_float(((unsigned int)u) << 16);
}

// R5 structure (best measured: 954 TF): BM=BN=256, BK=64; 512 thr = 8 waves
// (2M x 4N), wave tile 128x64, MFMA 16x16x32, 2 LDS slots, 4 k-slice phases
// with P/Q reg double-buffer + counted lgkmcnt(6), XOR-swizzled LDS.
// OUT_MODE: 0=bf16 rowmajor, 1=f32 rowmajor, 2=bf16 conv (col=(b,pix)),
//           3=f32 conv alpha*(acc+bias)+resid,
//           4=f32 conv-by-z: out[z*C*HW + row*HW + col] =
//             alpha*(acc + aux1[row]*aux2[z*256+col] + bias[row]) + resid[...]
// BIAS_MODE: 0=none, 1=bias[col], 2=bias[row]
// ORDER: 0 = m-fastest (B operand large), 1 = n-fastest (A operand large)
template<int OUT_MODE, int BIAS_MODE, int ORDER>
__global__ __launch_bounds__(512, 2) void gemm_q(
    const __hip_bfloat16* __restrict__ A,
    const __hip_bfloat16* __restrict__ Bt,
    void* __restrict__ outp,
    const float* __restrict__ bias,
    const float* __restrict__ resid,
    const float* __restrict__ alphap,
    const float* __restrict__ aux1,
    const float* __restrict__ aux2,
    int M, int N, int K,
    int ldA, int ldB, long sA, long sB, long sC, int ldC)
{
    extern __shared__ char smem[];   // 2 slots x 65536
    const int t = threadIdx.x;
    const int w = t >> 6, l = t & 63;
    const int q = l >> 4, r16 = l & 15;
    const int wr = w >> 2, wc = w & 3;   // 2M x 4N waves
    const int z = blockIdx.z;
    const int nbm = M >> 8, nbn = N >> 8;
    const int nwg = nbm * nbn;
    int f = blockIdx.x;
    {   // bijective XCD swizzle (m204)
        const int q8 = nwg >> 3, r8 = nwg & 7;
        const int xcd = f & 7, rank = f >> 3;
        f = (xcd < r8 ? xcd * (q8 + 1) : r8 * (q8 + 1) + (xcd - r8) * q8) + rank;
    }
    long m0, n0;
    if (ORDER == 0) { m0 = (long)(f % nbm) << 8; n0 = (long)(f / nbm) << 8; }
    else            { n0 = (long)(f % nbn) << 8; m0 = (long)(f / nbn) << 8; }
    const char* Azb = (const char*)(A + (long)z * sA);
    const char* Bzb = (const char*)(Bt + (long)z * sB);

    // staging addresses (advance +128B per K-tile); inverse-swizzled source
    const char* pa[4];
    const char* pb[4];
    int ldsd[4];
    #pragma unroll
    for (int i = 0; i < 4; ++i) {
        const int d = i * 8192 + t * 16;
        const int row = d >> 7;
        const int cb = (d & 127) ^ ((row & 7) << 4);
        pa[i] = Azb + ((m0 + row) * (long)ldA) * 2 + cb;
        pb[i] = Bzb + ((n0 + row) * (long)ldB) * 2 + cb;
        ldsd[i] = d;
    }
    auto stage = [&](int slot) {
        char* base = smem + slot * 65536;
        #pragma unroll
        for (int i = 0; i < 4; ++i) GLD16(pa[i], base + ldsd[i]);
        #pragma unroll
        for (int i = 0; i < 4; ++i) GLD16(pb[i], base + 32768 + ldsd[i]);
        #pragma unroll
        for (int i = 0; i < 4; ++i) { pa[i] += 128; pb[i] += 128; }
    };

    // hoisted LDS read offsets
    const int mask = (l & 7) << 4;
    const int s0 = ((l >> 5) << 4) ^ mask;   // note: for 16x16 path use q-based
    (void)s0;
    const int cx  = (q << 4) ^ mask;
    int offA[2], offB[2];
    offA[0] = (wr * 128 + r16) * 128 + cx;          // kk0 base (+ mih*8192 + j*2048)
    offA[1] = (wr * 128 + r16) * 128 + (cx ^ 64);   // kk1
    offB[0] = 32768 + (wc * 64 + r16) * 128 + cx;
    offB[1] = 32768 + (wc * 64 + r16) * 128 + (cx ^ 64);

#define DSA(dst, bs_, mih, kk) do { const char* p_ = (bs_) + offA[kk] + (mih) * 8192; \
    dst[0] = *(const bf16x8*)(p_);        dst[1] = *(const bf16x8*)(p_ + 2048); \
    dst[2] = *(const bf16x8*)(p_ + 4096); dst[3] = *(const bf16x8*)(p_ + 6144); } while (0)
#define DSB(dst, bs_, kk) do { const char* p_ = (bs_) + offB[kk]; \
    dst[0] = *(const bf16x8*)(p_);        dst[1] = *(const bf16x8*)(p_ + 2048); \
    dst[2] = *(const bf16x8*)(p_ + 4096); dst[3] = *(const bf16x8*)(p_ + 6144); } while (0)
#define MM16(ar, br, mih) do { __builtin_amdgcn_s_setprio(1); \
    _Pragma("unroll") for (int j = 0; j < 4; ++j) \
    _Pragma("unroll") for (int ni = 0; ni < 4; ++ni) \
        acc[(mih) * 4 + j][ni] = __builtin_amdgcn_mfma_f32_16x16x32_bf16( \
            ar[j], br[ni], acc[(mih) * 4 + j][ni], 0, 0, 0); \
    __builtin_amdgcn_s_setprio(0); SBAR(); } while (0)

    f32x4 acc[8][4] = {};
    const int nK = K >> 6;
    stage(0);

    for (int tk = 0; tk < nK; ++tk) {
        const int s = tk & 1;
        asm volatile("s_waitcnt vmcnt(0)" ::: "memory");
        SBAR();
        __builtin_amdgcn_s_barrier();
        SBAR();
        if (tk + 1 < nK) stage(s ^ 1);
        SBAR();

        const char* bs_ = smem + s * 65536;
        bf16x8 aP[4], bP[4], aQ[4], bQ[4];
        DSB(bP, bs_, 0); DSA(aP, bs_, 0, 0);     // ph0: kk0 mi0-3
        DSA(aQ, bs_, 1, 0);                      // ph1 reads in flight (kk0 mi4-7)
        WAIT_LGKM(4);  MM16(aP, bP, 0);
        DSB(bQ, bs_, 1); DSA(aP, bs_, 0, 1);     // ph2 reads (kk1 mi0-3)
        WAIT_LGKM(8);  MM16(aQ, bP, 1);
        DSA(aQ, bs_, 1, 1);                      // ph3 reads (kk1 mi4-7)
        WAIT_LGKM(4);  MM16(aP, bQ, 0);
        WAIT_LGKM(0);  MM16(aQ, bQ, 1);
        asm volatile("s_waitcnt lgkmcnt(0)" ::: "memory");
        SBAR();
        __builtin_amdgcn_s_barrier();
        SBAR();
    }

    const float alpha = (OUT_MODE >= 3) ? alphap[0] : 0.0f;
    #pragma unroll
    for (int mi = 0; mi < 8; ++mi) {
        #pragma unroll
        for (int ni = 0; ni < 4; ++ni) {
            #pragma unroll
            for (int r = 0; r < 4; ++r) {
                const long row = m0 + wr * 128 + mi * 16 + q * 4 + r;
                const long col = n0 + wc * 64 + ni * 16 + r16;
                float vv = acc[mi][ni][r];
                if (BIAS_MODE == 1) vv += bias[col];
                if (BIAS_MODE == 2) vv += bias[row];
                if (OUT_MODE == 0) {
                    ((__hip_bfloat16*)outp)[(long)z * sC + row * ldC + col] = __float2bfloat16(vv);
                } else if (OUT_MODE == 1) {
                    ((float*)outp)[(long)z * sC + row * ldC + col] = vv;
                } else if (OUT_MODE == 2) {
                    const long addr = (col >> 8) * (long)(kC * kHW) + row * kHW + (col & 255);
                    ((__hip_bfloat16*)outp)[addr] = __float2bfloat16(vv);
                } else if (OUT_MODE == 3) {
                    const long addr = (col >> 8) * (long)(kC * kHW) + row * kHW + (col & 255);
                    ((float*)outp)[addr] = alpha * vv + resid[addr];
                } else {  // OUT_MODE == 4: PV epilogue
                    const long addr = (long)z * (kC * kHW) + row * kHW + col;
                    const float term = vv + aux1[row] * aux2[(long)z * 256 + col] + bias[row];
                    ((float*)outp)[addr] = alpha * term + resid[addr];
                }
            }
        }
    }
#undef DSA
#undef DSB
#undef MM16
}

// x (B, C, HW) f32  ->  xT (B*HW, C) bf16
__global__ __launch_bounds__(256) void transpose_x(
    const float* __restrict__ x, __hip_bfloat16* __restrict__ xT)
{
    __shared__ float tile[64][65];
    const int b = blockIdx.z;
    const int c0 = blockIdx.x * 64;
    const int p0 = blockIdx.y * 64;
    const int tj = threadIdx.x & 63;
    const int ti = threadIdx.x >> 6;
    const float* xb = x + ((long)b * kC + c0) * kHW + p0;
    #pragma unroll
    for (int i = 0; i < 16; ++i) {
        const int c = i * 4 + ti;
        tile[c][tj] = xb[(long)c * kHW + tj];
    }
    __syncthreads();
    __hip_bfloat16* o = xT + ((long)(b * kHW + p0)) * kC + c0;
    #pragma unroll
    for (int i = 0; i < 16; ++i) {
        const int p = i * 4 + ti;
        o[(long)p * kC + tj] = __float2bfloat16(tile[tj][p]);
    }
}

// W (1280,1280) f32 -> WT (1280,1280) bf16, WT[c][o] = W[o][c]
__global__ __launch_bounds__(256) void transpose_w(
    const float* __restrict__ W, __hip_bfloat16* __restrict__ WT)
{
    __shared__ float tile[64][65];
    const int o0 = blockIdx.x * 64;
    const int c0 = blockIdx.y * 64;
    const int tj = threadIdx.x & 63;
    const int ti = threadIdx.x >> 6;
    #pragma unroll
    for (int i = 0; i < 16; ++i) {
        const int o = i * 4 + ti;
        tile[o][tj] = W[(long)(o0 + o) * kC + c0 + tj];
    }
    __syncthreads();
    #pragma unroll
    for (int i = 0; i < 16; ++i) {
        const int c = i * 4 + ti;
        WT[(long)(c0 + c) * kC + o0 + tj] = __float2bfloat16(tile[tj][c]);
    }
}

__global__ __launch_bounds__(256) void convert_f32_bf16(
    const float* __restrict__ s, __hip_bfloat16* __restrict__ d)
{
    const int i = (blockIdx.x * 256 + threadIdx.x) * 4;
    const float4 f = *reinterpret_cast<const float4*>(s + i);
    d[i + 0] = __float2bfloat16(f.x);
    d[i + 1] = __float2bfloat16(f.y);
    d[i + 2] = __float2bfloat16(f.z);
    d[i + 3] = __float2bfloat16(f.w);
}

// y=0: w1[c] = sum_o Wk[o][c]*bq[o];  y=1: w2[c] = sum_o Wq[o][c]*bk[o]
__global__ __launch_bounds__(256) void gemv_col(
    const float* __restrict__ Wk, const float* __restrict__ bq,
    const float* __restrict__ Wq, const float* __restrict__ bk,
    float* __restrict__ w1, float* __restrict__ w2)
{
    const float* W = blockIdx.y ? Wq : Wk;
    const float* v = blockIdx.y ? bk : bq;
    float* out = blockIdx.y ? w2 : w1;
    const int lj = threadIdx.x & 63;
    const int wid = threadIdx.x >> 6;
    const int c = blockIdx.x * 64 + lj;
    __shared__ float red[4][64];
    float s = 0.0f;
    for (int o = wid * 320; o < (wid + 1) * 320; ++o)
        s += W[(long)o * kC + c] * v[o];
    red[wid][lj] = s;
    __syncthreads();
    if (wid == 0) out[c] = red[0][lj] + red[1][lj] + red[2][lj] + red[3][lj];
}

// wrbv[o] = sum_j Wr[o][j]*bv[j]   (grid 320, 4 rows/block)
__global__ __launch_bounds__(256) void gemv_row(
    const float* __restrict__ Wr, const float* __restrict__ bv, float* __restrict__ out)
{
    const int wid = threadIdx.x >> 6, lj = threadIdx.x & 63;
    const int o = blockIdx.x * 4 + wid;
    float s = 0.0f;
    #pragma unroll
    for (int j = 0; j < 20; ++j)
        s += Wr[(long)o * kC + j * 64 + lj] * bv[j * 64 + lj];
    #pragma unroll
    for (int off = 32; off > 0; off >>= 1) s += __shfl_down(s, off);
    if (lj == 0) out[o] = s;
}

// c0 = dot(bk, bq) over 1280
__global__ __launch_bounds__(256) void dot_k(
    const float* __restrict__ a, const float* __restrict__ b, float* __restrict__ out)
{
    __shared__ float red[256];
    const int t_ = threadIdx.x;
    float s = 0.0f;
    for (int j = t_; j < kC; j += 256) s += a[j] * b[j];
    red[t_] = s; __syncthreads();
    for (int off = 128; off > 0; off >>= 1) {
        if (t_ < off) red[t_] += red[t_ + off];
        __syncthreads();
    }
    if (t_ == 0) out[0] = red[0];
}

// c2s[p] = sum_c xT[p][c]*w2[c]   (wave per row; grid 8192 x 4 waves)
__global__ __launch_bounds__(256) void row_dot_x(
    const __hip_bfloat16* __restrict__ xT, const float* __restrict__ w2,
    float* __restrict__ c2s)
{
    const int wid = threadIdx.x >> 6, lj = threadIdx.x & 63;
    const long p = (long)blockIdx.x * 4 + wid;
    const ushort4* base = (const ushort4*)((const char*)xT + p * 2560 + lj * 40);
    float s = 0.0f;
    #pragma unroll
    for (int j = 0; j < 5; ++j) {
        const ushort4 v = base[j];
        const int c0 = lj * 20 + j * 4;
        s += bf2f(v.x) * w2[c0] + bf2f(v.y) * w2[c0 + 1]
           + bf2f(v.z) * w2[c0 + 2] + bf2f(v.w) * w2[c0 + 3];
    }
    #pragma unroll
    for (int off = 32; off > 0; off >>= 1) s += __shfl_down(s, off);
    if (lj == 0) c2s[p] = s;
}

// rs[p] = sum_m attn[p*256 + m]   (wave per row)
__global__ __launch_bounds__(256) void rowsum_attn(
    const __hip_bfloat16* __restrict__ attn, float* __restrict__ rs)
{
    const int wid = threadIdx.x >> 6, lj = threadIdx.x & 63;
    const long p = (long)blockIdx.x * 4 + wid;
    const ushort4 v = *(const ushort4*)((const char*)attn + p * 512 + lj * 8);
    float s = bf2f(v.x) + bf2f(v.y) + bf2f(v.z) + bf2f(v.w);
    #pragma unroll
    for (int off = 32; off > 0; off >>= 1) s += __shfl_down(s, off);
    if (lj == 0) rs[p] = s;
}

// softmax over BATCH axis with rank-1 corrections:
// s[b] = sc[b*65536+pos] + c2s[b*256 + (pos&255)] + c0
__global__ __launch_bounds__(256) void softmax_batch(
    const float* __restrict__ sc, __hip_bfloat16* __restrict__ attn,
    const float* __restrict__ c2s, const float* __restrict__ c0p)
{
    const int pos = blockIdx.x * 256 + threadIdx.x;
    const int mcol = pos & 255;
    const float c0v = c0p[0];
    float m = -3.0e38f, s = 0.0f;
    for (int b = 0; b < kB; ++b) {
        const float v = sc[(long)b * 65536 + pos] + c2s[b * 256 + mcol] + c0v;
        const float mn = fmaxf(m, v);
        s = s * __expf(m - mn) + __expf(v - mn);
        m = mn;
    }
    const float rinv = 1.0f / s;
    for (int b = 0; b < kB; ++b) {
        const float v = sc[(long)b * 65536 + pos] + c2s[b * 256 + mcol] + c0v;
        attn[(long)b * 65536 + pos] = __float2bfloat16(__expf(v - m) * rinv);
    }
}

extern "C" void kernel_launch(void* const* d_in, const int* in_sizes, int n_in,
                              void* d_out, int out_size, void* d_ws, size_t ws_size,
                              hipStream_t stream)
{
    const float* x  = (const float*)d_in[0];
    const float* Wk = (const float*)d_in[1];
    const float* bk = (const float*)d_in[2];
    const float* Wq = (const float*)d_in[3];
    const float* bq = (const float*)d_in[4];
    const float* Wv = (const float*)d_in[5];
    const float* bv = (const float*)d_in[6];
    const float* Wr = (const float*)d_in[7];
    const float* br = (const float*)d_in[8];
    const float* al = (const float*)d_in[9];

    char* ws = (char*)d_ws;
    __hip_bfloat16* xT   = (__hip_bfloat16*)(ws);               // (32768,1280) 83.9MB
    __hip_bfloat16* uT   = (__hip_bfloat16*)(ws + 83886080L);   // (32768,1280) 83.9MB
    __hip_bfloat16* rv   = (__hip_bfloat16*)(ws + 167772160L);  // conv (B,C,HW) 83.9MB
    float*          sc   = (float*)(ws + 251658240L);           // (B,256,256) f32 33.5MB
    __hip_bfloat16* attn = (__hip_bfloat16*)(ws + 285212672L);  // (B,256,256) 16.8MB
    __hip_bfloat16* WkT  = (__hip_bfloat16*)(ws + 301989888L);  // 3.28MB each
    __hip_bfloat16* Wrb  = (__hip_bfloat16*)(ws + 305266688L);
    __hip_bfloat16* WqT  = (__hip_bfloat16*)(ws + 308543488L);
    __hip_bfloat16* WvT  = (__hip_bfloat16*)(ws + 311820288L);
    __hip_bfloat16* G    = (__hip_bfloat16*)(ws + 315097088L);
    __hip_bfloat16* W2   = (__hip_bfloat16*)(ws + 318373888L);
    float*          w1   = (float*)(ws + 321650688L);
    float*          w2v  = (float*)(ws + 321655808L);
    float*          wrbv = (float*)(ws + 321660928L);
    float*          c0b  = (float*)(ws + 321666048L);
    float*          c2s  = (float*)(ws + 321666560L);           // 32768 f32
    float*          rs   = (float*)(ws + 321797632L);           // 32768 f32

    const int SMEM = 131072;
    hipFuncSetAttribute((const void*)gemm_q<0,0,0>, hipFuncAttributeMaxDynamicSharedMemorySize, SMEM);
    hipFuncSetAttribute((const void*)gemm_q<0,1,1>, hipFuncAttributeMaxDynamicSharedMemorySize, SMEM);
    hipFuncSetAttribute((const void*)gemm_q<1,0,0>, hipFuncAttributeMaxDynamicSharedMemorySize, SMEM);
    hipFuncSetAttribute((const void*)gemm_q<2,0,0>, hipFuncAttributeMaxDynamicSharedMemorySize, SMEM);
    hipFuncSetAttribute((const void*)gemm_q<4,0,0>, hipFuncAttributeMaxDynamicSharedMemorySize, SMEM);

    // weight preprocessing
    convert_f32_bf16<<<1600, 256, 0, stream>>>(Wr, Wrb);
    transpose_w<<<dim3(20, 20), 256, 0, stream>>>(Wk, WkT);
    transpose_w<<<dim3(20, 20), 256, 0, stream>>>(Wq, WqT);
    transpose_w<<<dim3(20, 20), 256, 0, stream>>>(Wv, WvT);
    gemv_col<<<dim3(20, 2), 256, 0, stream>>>(Wk, bq, Wq, bk, w1, w2v);
    gemv_row<<<320, 256, 0, stream>>>(Wr, bv, wrbv);
    dot_k<<<1, 256, 0, stream>>>(bk, bq, c0b);
    transpose_x<<<dim3(20, 4, 128), 256, 0, stream>>>(x, xT);

    // G = Wk^T*Wq (z=0) and W2 = Wr*Wv (z=1), stacked: strides = 1638400 elems
    gemm_q<0, 0, 0><<<dim3(25, 1, 2), 512, SMEM, stream>>>(WkT, WqT, G,
        nullptr, nullptr, nullptr, nullptr, nullptr,
        1280, 1280, 1280, 1280, 1280, 1638400, 1638400, 1638400, 1280);
    // uT (32768,1280) = xT * G^T + w1[col]   (A large -> ORDER=1)
    gemm_q<0, 1, 1><<<dim3(640, 1, 1), 512, SMEM, stream>>>(xT, G, uT,
        w1, nullptr, nullptr, nullptr, nullptr,
        32768, 1280, 1280, 1280, 1280, 0, 0, 0, 1280);
    // c2s[p] = xT[p] . w2
    row_dot_x<<<8192, 256, 0, stream>>>(xT, w2v, c2s);
    // sc[b] (256,256) f32 = xT[b] * uT[b]^T
    gemm_q<1, 0, 0><<<dim3(1, 1, 128), 512, SMEM, stream>>>(xT, uT, sc,
        nullptr, nullptr, nullptr, nullptr, nullptr,
        256, 256, 1280, 1280, 1280, 327680, 327680, 65536, 256);
    softmax_batch<<<256, 256, 0, stream>>>(sc, attn, c2s, c0b);
    rowsum_attn<<<8192, 256, 0, stream>>>(attn, rs);
    // rv conv (B,C,HW) = W2 * x   (B operand xT large -> ORDER=0)
    gemm_q<2, 0, 0><<<dim3(640, 1, 1), 512, SMEM, stream>>>(W2, xT, rv,
        nullptr, nullptr, nullptr, nullptr, nullptr,
        1280, 32768, 1280, 1280, 1280, 0, 0, 0, 0);
    // out[b][c][n] = alpha*(sum_m rv[b][c][m]*attn[b][n][m] + wrbv[c]*rs[b,n] + br[c]) + x
    gemm_q<4, 0, 0><<<dim3(5, 1, 128), 512, SMEM, stream>>>(rv, attn, d_out,
        br, x, al, wrbv, rs,
        1280, 256, 256, 256, 256, 327680, 65536, 0, 0);
}

// Round 11
// 509.520 us; speedup vs baseline: 1.5211x; 1.0724x over previous
//
#include <hip/hip_runtime.h>
#include <hip/hip_bf16.h>

typedef __attribute__((ext_vector_type(8))) short bf16x8;
typedef __attribute__((ext_vector_type(4))) float f32x4;

#define GLD16(g, s) __builtin_amdgcn_global_load_lds( \
    (const __attribute__((address_space(1))) void*)(g), \
    (__attribute__((address_space(3))) void*)(s), 16, 0, 0)

#define SBAR() __builtin_amdgcn_sched_barrier(0)
#define WAIT_LGKM(n) do { asm volatile("s_waitcnt lgkmcnt(" #n ")" ::: "memory"); SBAR(); } while (0)

static constexpr int kB  = 128;
static constexpr int kC  = 1280;
static constexpr int kHW = 256;

__device__ __forceinline__ float bf2f(unsigned short u) {
    return __uint_as_float(((unsigned int)u) << 16);
}

// R5 structure (best measured: 954 TF at full grid): BM=BN=256, BK=64;
// 512 thr = 8 waves (2M x 4N), wave tile 128x64, MFMA 16x16x32, 2 LDS slots,
// 4 k-slice phases with P/Q reg double-buffer + counted lgkmcnt, XOR swizzle.
// OUT_MODE: 0=bf16 rowmajor, 1=f32 rowmajor, 2=bf16 conv (col=(b,pix)),
//           3=f32 conv alpha*(acc+bias)+resid,
//           4=f32 conv-by-z PV epilogue (rank-1 + bias + resid)
// BIAS_MODE: 0=none, 1=bias[col], 2=bias[row]
// ORDER: 0 = m-fastest (B operand large), 1 = n-fastest (A operand large)
template<int OUT_MODE, int BIAS_MODE, int ORDER>
__device__ __forceinline__ void gemm_body(
    const __hip_bfloat16* __restrict__ A,
    const __hip_bfloat16* __restrict__ Bt,
    void* __restrict__ outp,
    const float* __restrict__ bias,
    const float* __restrict__ resid,
    const float* __restrict__ alphap,
    const float* __restrict__ aux1,
    const float* __restrict__ aux2,
    int M, int N, int K,
    int ldA, int ldB, long sA, long sB, long sC, int ldC,
    char* smem, int z)
{
    const int t = threadIdx.x;
    const int w = t >> 6, l = t & 63;
    const int q = l >> 4, r16 = l & 15;
    const int wr = w >> 2, wc = w & 3;   // 2M x 4N waves
    const int nbm = M >> 8, nbn = N >> 8;
    const int nwg = nbm * nbn;
    int f = blockIdx.x;
    {   // bijective XCD swizzle (m204)
        const int q8 = nwg >> 3, r8 = nwg & 7;
        const int xcd = f & 7, rank = f >> 3;
        f = (xcd < r8 ? xcd * (q8 + 1) : r8 * (q8 + 1) + (xcd - r8) * q8) + rank;
    }
    long m0, n0;
    if (ORDER == 0) { m0 = (long)(f % nbm) << 8; n0 = (long)(f / nbm) << 8; }
    else            { n0 = (long)(f % nbn) << 8; m0 = (long)(f / nbn) << 8; }
    const char* Azb = (const char*)(A + (long)z * sA);
    const char* Bzb = (const char*)(Bt + (long)z * sB);

    // staging addresses (advance +128B per K-tile); inverse-swizzled source
    const char* pa[4];
    const char* pb[4];
    int ldsd[4];
    #pragma unroll
    for (int i = 0; i < 4; ++i) {
        const int d = i * 8192 + t * 16;
        const int row = d >> 7;
        const int cb = (d & 127) ^ ((row & 7) << 4);
        pa[i] = Azb + ((m0 + row) * (long)ldA) * 2 + cb;
        pb[i] = Bzb + ((n0 + row) * (long)ldB) * 2 + cb;
        ldsd[i] = d;
    }
    auto stage = [&](int slot) {
        char* base = smem + slot * 65536;
        #pragma unroll
        for (int i = 0; i < 4; ++i) GLD16(pa[i], base + ldsd[i]);
        #pragma unroll
        for (int i = 0; i < 4; ++i) GLD16(pb[i], base + 32768 + ldsd[i]);
        #pragma unroll
        for (int i = 0; i < 4; ++i) { pa[i] += 128; pb[i] += 128; }
    };

    // hoisted LDS read offsets
    const int mask = (l & 7) << 4;
    const int cx  = (q << 4) ^ mask;
    int offA[2], offB[2];
    offA[0] = (wr * 128 + r16) * 128 + cx;
    offA[1] = (wr * 128 + r16) * 128 + (cx ^ 64);
    offB[0] = 32768 + (wc * 64 + r16) * 128 + cx;
    offB[1] = 32768 + (wc * 64 + r16) * 128 + (cx ^ 64);

#define DSA(dst, bs_, mih, kk) do { const char* p_ = (bs_) + offA[kk] + (mih) * 8192; \
    dst[0] = *(const bf16x8*)(p_);        dst[1] = *(const bf16x8*)(p_ + 2048); \
    dst[2] = *(const bf16x8*)(p_ + 4096); dst[3] = *(const bf16x8*)(p_ + 6144); } while (0)
#define DSB(dst, bs_, kk) do { const char* p_ = (bs_) + offB[kk]; \
    dst[0] = *(const bf16x8*)(p_);        dst[1] = *(const bf16x8*)(p_ + 2048); \
    dst[2] = *(const bf16x8*)(p_ + 4096); dst[3] = *(const bf16x8*)(p_ + 6144); } while (0)
#define MM16(ar, br, mih) do { __builtin_amdgcn_s_setprio(1); \
    _Pragma("unroll") for (int j = 0; j < 4; ++j) \
    _Pragma("unroll") for (int ni = 0; ni < 4; ++ni) \
        acc[(mih) * 4 + j][ni] = __builtin_amdgcn_mfma_f32_16x16x32_bf16( \
            ar[j], br[ni], acc[(mih) * 4 + j][ni], 0, 0, 0); \
    __builtin_amdgcn_s_setprio(0); SBAR(); } while (0)

    f32x4 acc[8][4] = {};
    const int nK = K >> 6;
    stage(0);

    for (int tk = 0; tk < nK; ++tk) {
        const int s = tk & 1;
        asm volatile("s_waitcnt vmcnt(0)" ::: "memory");
        SBAR();
        __builtin_amdgcn_s_barrier();
        SBAR();
        if (tk + 1 < nK) stage(s ^ 1);
        SBAR();

        const char* bs_ = smem + s * 65536;
        bf16x8 aP[4], bP[4], aQ[4], bQ[4];
        DSB(bP, bs_, 0); DSA(aP, bs_, 0, 0);
        DSA(aQ, bs_, 1, 0);
        WAIT_LGKM(4);  MM16(aP, bP, 0);
        DSB(bQ, bs_, 1); DSA(aP, bs_, 0, 1);
        WAIT_LGKM(8);  MM16(aQ, bP, 1);
        DSA(aQ, bs_, 1, 1);
        WAIT_LGKM(4);  MM16(aP, bQ, 0);
        WAIT_LGKM(0);  MM16(aQ, bQ, 1);
        asm volatile("s_waitcnt lgkmcnt(0)" ::: "memory");
        SBAR();
        __builtin_amdgcn_s_barrier();
        SBAR();
    }

    const float alpha = (OUT_MODE >= 3) ? alphap[0] : 0.0f;
    #pragma unroll
    for (int mi = 0; mi < 8; ++mi) {
        #pragma unroll
        for (int ni = 0; ni < 4; ++ni) {
            #pragma unroll
            for (int r = 0; r < 4; ++r) {
                const long row = m0 + wr * 128 + mi * 16 + q * 4 + r;
                const long col = n0 + wc * 64 + ni * 16 + r16;
                float vv = acc[mi][ni][r];
                if (BIAS_MODE == 1) vv += bias[col];
                if (BIAS_MODE == 2) vv += bias[row];
                if (OUT_MODE == 0) {
                    ((__hip_bfloat16*)outp)[(long)z * sC + row * ldC + col] = __float2bfloat16(vv);
                } else if (OUT_MODE == 1) {
                    ((float*)outp)[(long)z * sC + row * ldC + col] = vv;
                } else if (OUT_MODE == 2) {
                    const long addr = (col >> 8) * (long)(kC * kHW) + row * kHW + (col & 255);
                    ((__hip_bfloat16*)outp)[addr] = __float2bfloat16(vv);
                } else if (OUT_MODE == 3) {
                    const long addr = (col >> 8) * (long)(kC * kHW) + row * kHW + (col & 255);
                    ((float*)outp)[addr] = alpha * vv + resid[addr];
                } else {  // OUT_MODE == 4: PV epilogue
                    const long addr = (long)z * (kC * kHW) + row * kHW + col;
                    const float term = vv + aux1[row] * aux2[(long)z * 256 + col] + bias[row];
                    ((float*)outp)[addr] = alpha * term + resid[addr];
                }
            }
        }
    }
#undef DSA
#undef DSB
#undef MM16
}

template<int OUT_MODE, int BIAS_MODE, int ORDER>
__global__ __launch_bounds__(512, 2) void gemm_q(
    const __hip_bfloat16* __restrict__ A,
    const __hip_bfloat16* __restrict__ Bt,
    void* __restrict__ outp,
    const float* __restrict__ bias,
    const float* __restrict__ resid,
    const float* __restrict__ alphap,
    const float* __restrict__ aux1,
    const float* __restrict__ aux2,
    int M, int N, int K,
    int ldA, int ldB, long sA, long sB, long sC, int ldC)
{
    extern __shared__ char smem[];
    gemm_body<OUT_MODE, BIAS_MODE, ORDER>(A, Bt, outp, bias, resid, alphap,
        aux1, aux2, M, N, K, ldA, ldB, sA, sB, sC, ldC, smem, blockIdx.z);
}

// Dual dispatch: z=0 -> uT = xT*G^T + w1 (32768x1280, ORDER=1);
//                z=1 -> rv conv = W2*xT^T (1280x32768, ORDER=0).
// 640 blocks x 2 z = 1280 = exactly 5 full block-waves (no tail).
__global__ __launch_bounds__(512, 2) void gemm_dual(
    const __hip_bfloat16* __restrict__ xT,
    const __hip_bfloat16* __restrict__ G,
    __hip_bfloat16* __restrict__ uT,
    const float* __restrict__ w1,
    const __hip_bfloat16* __restrict__ W2,
    __hip_bfloat16* __restrict__ rv)
{
    extern __shared__ char smem[];
    if (blockIdx.z == 0) {
        gemm_body<0, 1, 1>(xT, G, uT, w1, nullptr, nullptr, nullptr, nullptr,
            32768, 1280, 1280, 1280, 1280, 0, 0, 0, 1280, smem, 0);
    } else {
        gemm_body<2, 0, 0>(W2, xT, rv, nullptr, nullptr, nullptr, nullptr, nullptr,
            1280, 32768, 1280, 1280, 1280, 0, 0, 0, 0, smem, 0);
    }
}

// x (B, C, HW) f32 -> xT (B*HW, C) bf16; fused partial c2s[p] += sum_c x[c][p]*w2[c]
__global__ __launch_bounds__(256) void transpose_x(
    const float* __restrict__ x, __hip_bfloat16* __restrict__ xT,
    const float* __restrict__ w2, float* __restrict__ c2s)
{
    __shared__ float tile[64][65];
    __shared__ float red[4][64];
    const int b = blockIdx.z;
    const int c0 = blockIdx.x * 64;
    const int p0 = blockIdx.y * 64;
    const int tj = threadIdx.x & 63;
    const int ti = threadIdx.x >> 6;
    const float* xb = x + ((long)b * kC + c0) * kHW + p0;
    #pragma unroll
    for (int i = 0; i < 16; ++i) {
        const int c = i * 4 + ti;
        tile[c][tj] = xb[(long)c * kHW + tj];
    }
    __syncthreads();
    __hip_bfloat16* o = xT + ((long)(b * kHW + p0)) * kC + c0;
    #pragma unroll
    for (int i = 0; i < 16; ++i) {
        const int p = i * 4 + ti;
        o[(long)p * kC + tj] = __float2bfloat16(tile[tj][p]);
    }
    // fused c2s partial: thread (ti, p=tj) sums 16 channels
    float s = 0.0f;
    #pragma unroll
    for (int j = 0; j < 16; ++j)
        s += tile[ti * 16 + j][tj] * w2[c0 + ti * 16 + j];
    red[ti][tj] = s;
    __syncthreads();
    if (ti == 0)
        atomicAdd(&c2s[b * 256 + p0 + tj], red[0][tj] + red[1][tj] + red[2][tj] + red[3][tj]);
}

// W (1280,1280) f32 -> WT bf16 (z selects among 3 weight pairs)
__global__ __launch_bounds__(256) void transpose_w3(
    const float* __restrict__ Wk, __hip_bfloat16* __restrict__ WkT,
    const float* __restrict__ Wq, __hip_bfloat16* __restrict__ WqT,
    const float* __restrict__ Wv, __hip_bfloat16* __restrict__ WvT)
{
    const float* W = (blockIdx.z == 0) ? Wk : (blockIdx.z == 1) ? Wq : Wv;
    __hip_bfloat16* WT = (blockIdx.z == 0) ? WkT : (blockIdx.z == 1) ? WqT : WvT;
    __shared__ float tile[64][65];
    const int o0 = blockIdx.x * 64;
    const int c0 = blockIdx.y * 64;
    const int tj = threadIdx.x & 63;
    const int ti = threadIdx.x >> 6;
    #pragma unroll
    for (int i = 0; i < 16; ++i) {
        const int o = i * 4 + ti;
        tile[o][tj] = W[(long)(o0 + o) * kC + c0 + tj];
    }
    __syncthreads();
    #pragma unroll
    for (int i = 0; i < 16; ++i) {
        const int c = i * 4 + ti;
        WT[(long)(c0 + c) * kC + o0 + tj] = __float2bfloat16(tile[tj][c]);
    }
}

__global__ __launch_bounds__(256) void convert_f32_bf16(
    const float* __restrict__ s, __hip_bfloat16* __restrict__ d)
{
    const int i = (blockIdx.x * 256 + threadIdx.x) * 4;
    const float4 f = *reinterpret_cast<const float4*>(s + i);
    d[i + 0] = __float2bfloat16(f.x);
    d[i + 1] = __float2bfloat16(f.y);
    d[i + 2] = __float2bfloat16(f.z);
    d[i + 3] = __float2bfloat16(f.w);
}

__global__ __launch_bounds__(256) void zero_f32(float* __restrict__ p)
{
    reinterpret_cast<float4*>(p)[blockIdx.x * 256 + threadIdx.x] =
        make_float4(0.f, 0.f, 0.f, 0.f);
}

// y=0: w1[c] = sum_o Wk[o][c]*bq[o];  y=1: w2[c] = sum_o Wq[o][c]*bk[o]
__global__ __launch_bounds__(256) void gemv_col(
    const float* __restrict__ Wk, const float* __restrict__ bq,
    const float* __restrict__ Wq, const float* __restrict__ bk,
    float* __restrict__ w1, float* __restrict__ w2)
{
    const float* W = blockIdx.y ? Wq : Wk;
    const float* v = blockIdx.y ? bk : bq;
    float* out = blockIdx.y ? w2 : w1;
    const int lj = threadIdx.x & 63;
    const int wid = threadIdx.x >> 6;
    const int c = blockIdx.x * 64 + lj;
    __shared__ float red[4][64];
    float s = 0.0f;
    for (int o = wid * 320; o < (wid + 1) * 320; ++o)
        s += W[(long)o * kC + c] * v[o];
    red[wid][lj] = s;
    __syncthreads();
    if (wid == 0) out[c] = red[0][lj] + red[1][lj] + red[2][lj] + red[3][lj];
}

// wrbv[o] = sum_j Wr[o][j]*bv[j]
__global__ __launch_bounds__(256) void gemv_row(
    const float* __restrict__ Wr, const float* __restrict__ bv, float* __restrict__ out)
{
    const int wid = threadIdx.x >> 6, lj = threadIdx.x & 63;
    const int o = blockIdx.x * 4 + wid;
    float s = 0.0f;
    #pragma unroll
    for (int j = 0; j < 20; ++j)
        s += Wr[(long)o * kC + j * 64 + lj] * bv[j * 64 + lj];
    #pragma unroll
    for (int off = 32; off > 0; off >>= 1) s += __shfl_down(s, off);
    if (lj == 0) out[o] = s;
}

// c0 = dot(bk, bq)
__global__ __launch_bounds__(256) void dot_k(
    const float* __restrict__ a, const float* __restrict__ b, float* __restrict__ out)
{
    __shared__ float red[256];
    const int t_ = threadIdx.x;
    float s = 0.0f;
    for (int j = t_; j < kC; j += 256) s += a[j] * b[j];
    red[t_] = s; __syncthreads();
    for (int off = 128; off > 0; off >>= 1) {
        if (t_ < off) red[t_] += red[t_ + off];
        __syncthreads();
    }
    if (t_ == 0) out[0] = red[0];
}

// rs[p] = sum_m attn[p*256 + m]
__global__ __launch_bounds__(256) void rowsum_attn(
    const __hip_bfloat16* __restrict__ attn, float* __restrict__ rs)
{
    const int wid = threadIdx.x >> 6, lj = threadIdx.x & 63;
    const long p = (long)blockIdx.x * 4 + wid;
    const ushort4 v = *(const ushort4*)((const char*)attn + p * 512 + lj * 8);
    float s = bf2f(v.x) + bf2f(v.y) + bf2f(v.z) + bf2f(v.w);
    #pragma unroll
    for (int off = 32; off > 0; off >>= 1) s += __shfl_down(s, off);
    if (lj == 0) rs[p] = s;
}

// softmax over BATCH axis with rank-1 corrections
__global__ __launch_bounds__(256) void softmax_batch(
    const float* __restrict__ sc, __hip_bfloat16* __restrict__ attn,
    const float* __restrict__ c2s, const float* __restrict__ c0p)
{
    const int pos = blockIdx.x * 256 + threadIdx.x;
    const int mcol = pos & 255;
    const float c0v = c0p[0];
    float m = -3.0e38f, s = 0.0f;
    for (int b = 0; b < kB; ++b) {
        const float v = sc[(long)b * 65536 + pos] + c2s[b * 256 + mcol] + c0v;
        const float mn = fmaxf(m, v);
        s = s * __expf(m - mn) + __expf(v - mn);
        m = mn;
    }
    const float rinv = 1.0f / s;
    for (int b = 0; b < kB; ++b) {
        const float v = sc[(long)b * 65536 + pos] + c2s[b * 256 + mcol] + c0v;
        attn[(long)b * 65536 + pos] = __float2bfloat16(__expf(v - m) * rinv);
    }
}

extern "C" void kernel_launch(void* const* d_in, const int* in_sizes, int n_in,
                              void* d_out, int out_size, void* d_ws, size_t ws_size,
                              hipStream_t stream)
{
    const float* x  = (const float*)d_in[0];
    const float* Wk = (const float*)d_in[1];
    const float* bk = (const float*)d_in[2];
    const float* Wq = (const float*)d_in[3];
    const float* bq = (const float*)d_in[4];
    const float* Wv = (const float*)d_in[5];
    const float* bv = (const float*)d_in[6];
    const float* Wr = (const float*)d_in[7];
    const float* br = (const float*)d_in[8];
    const float* al = (const float*)d_in[9];

    char* ws = (char*)d_ws;
    __hip_bfloat16* xT   = (__hip_bfloat16*)(ws);               // (32768,1280) 83.9MB
    __hip_bfloat16* uT   = (__hip_bfloat16*)(ws + 83886080L);   // (32768,1280) 83.9MB
    __hip_bfloat16* rv   = (__hip_bfloat16*)(ws + 167772160L);  // conv (B,C,HW) 83.9MB
    float*          sc   = (float*)(ws + 251658240L);           // (B,256,256) f32 33.5MB
    __hip_bfloat16* attn = (__hip_bfloat16*)(ws + 285212672L);  // (B,256,256) 16.8MB
    __hip_bfloat16* WkT  = (__hip_bfloat16*)(ws + 301989888L);  // 3.28MB each
    __hip_bfloat16* Wrb  = (__hip_bfloat16*)(ws + 305266688L);
    __hip_bfloat16* WqT  = (__hip_bfloat16*)(ws + 308543488L);
    __hip_bfloat16* WvT  = (__hip_bfloat16*)(ws + 311820288L);
    __hip_bfloat16* G    = (__hip_bfloat16*)(ws + 315097088L);
    __hip_bfloat16* W2   = (__hip_bfloat16*)(ws + 318373888L);
    float*          w1   = (float*)(ws + 321650688L);
    float*          w2v  = (float*)(ws + 321655808L);
    float*          wrbv = (float*)(ws + 321660928L);
    float*          c0b  = (float*)(ws + 321666048L);
    float*          c2s  = (float*)(ws + 321666560L);           // 32768 f32
    float*          rs   = (float*)(ws + 321797632L);           // 32768 f32

    const int SMEM = 131072;
    hipFuncSetAttribute((const void*)gemm_q<0,0,0>, hipFuncAttributeMaxDynamicSharedMemorySize, SMEM);
    hipFuncSetAttribute((const void*)gemm_q<1,0,0>, hipFuncAttributeMaxDynamicSharedMemorySize, SMEM);
    hipFuncSetAttribute((const void*)gemm_q<4,0,0>, hipFuncAttributeMaxDynamicSharedMemorySize, SMEM);
    hipFuncSetAttribute((const void*)gemm_dual,     hipFuncAttributeMaxDynamicSharedMemorySize, SMEM);

    // weight preprocessing
    convert_f32_bf16<<<1600, 256, 0, stream>>>(Wr, Wrb);
    transpose_w3<<<dim3(20, 20, 3), 256, 0, stream>>>(Wk, WkT, Wq, WqT, Wv, WvT);
    gemv_col<<<dim3(20, 2), 256, 0, stream>>>(Wk, bq, Wq, bk, w1, w2v);
    gemv_row<<<320, 256, 0, stream>>>(Wr, bv, wrbv);
    dot_k<<<1, 256, 0, stream>>>(bk, bq, c0b);
    zero_f32<<<32, 256, 0, stream>>>(c2s);
    transpose_x<<<dim3(20, 4, 128), 256, 0, stream>>>(x, xT, w2v, c2s);

    // G = Wk^T*Wq (z=0) and W2 = Wr*Wv (z=1), stacked: strides = 1638400 elems
    gemm_q<0, 0, 0><<<dim3(25, 1, 2), 512, SMEM, stream>>>(WkT, WqT, G,
        nullptr, nullptr, nullptr, nullptr, nullptr,
        1280, 1280, 1280, 1280, 1280, 1638400, 1638400, 1638400, 1280);
    // dual: uT = xT*G^T + w1  |  rv = W2*x (conv); 1280 blocks = 5 full waves
    gemm_dual<<<dim3(640, 1, 2), 512, SMEM, stream>>>(xT, G, uT, w1, W2, rv);
    // sc[b] (256,256) f32 = xT[b] * uT[b]^T
    gemm_q<1, 0, 0><<<dim3(1, 1, 128), 512, SMEM, stream>>>(xT, uT, sc,
        nullptr, nullptr, nullptr, nullptr, nullptr,
        256, 256, 1280, 1280, 1280, 327680, 327680, 65536, 256);
    softmax_batch<<<256, 256, 0, stream>>>(sc, attn, c2s, c0b);
    rowsum_attn<<<8192, 256, 0, stream>>>(attn, rs);
    // out[b][c][n] = alpha*(sum_m rv[b][c][m]*attn[b][n][m] + wrbv[c]*rs[b,n] + br[c]) + x
    gemm_q<4, 0, 0><<<dim3(5, 1, 128), 512, SMEM, stream>>>(rv, attn, d_out,
        br, x, al, wrbv, rs,
        1280, 256, 256, 256, 256, 327680, 65536, 0, 0);
}

// Round 12
// 507.713 us; speedup vs baseline: 1.5265x; 1.0036x over previous
//
#include <hip/hip_runtime.h>
#include <hip/hip_bf16.h>

typedef __attribute__((ext_vector_type(8))) short bf16x8;
typedef __attribute__((ext_vector_type(4))) float f32x4;

#define GLD16(g, s) __builtin_amdgcn_global_load_lds( \
    (const __attribute__((address_space(1))) void*)(g), \
    (__attribute__((address_space(3))) void*)(s), 16, 0, 0)

#define SBAR() __builtin_amdgcn_sched_barrier(0)
#define WAIT_LGKM(n) do { asm volatile("s_waitcnt lgkmcnt(" #n ")" ::: "memory"); SBAR(); } while (0)

static constexpr int kB  = 128;
static constexpr int kC  = 1280;
static constexpr int kHW = 256;

__device__ __forceinline__ float bf2f(unsigned short u) {
    return __uint_as_float(((unsigned int)u) << 16);
}

// Best-measured structure (1013 TF in dual): BM=BN=256, BK=64; 512 thr =
// 8 waves (2M x 4N), wave tile 128x64, MFMA 16x16x32, 2 LDS slots, 4 k-slice
// phases with P/Q reg double-buffer + counted lgkmcnt, XOR-swizzled LDS.
// OUT_MODE: 0=bf16 rowmajor, 1=f32 rowmajor, 2=bf16 conv (col=(b,pix)),
//           3=f32 conv alpha*(acc+bias)+resid,
//           4=f32 conv-by-z PV epilogue (rank-1 + bias + resid)
// BIAS_MODE: 0=none, 1=bias[col], 2=bias[row]
// ORDER: 0 = m-fastest (B operand large), 1 = n-fastest (A operand large)
template<int OUT_MODE, int BIAS_MODE, int ORDER>
__device__ __forceinline__ void gemm_body(
    const __hip_bfloat16* __restrict__ A,
    const __hip_bfloat16* __restrict__ Bt,
    void* __restrict__ outp,
    const float* __restrict__ bias,
    const float* __restrict__ resid,
    const float* __restrict__ alphap,
    const float* __restrict__ aux1,
    const float* __restrict__ aux2,
    int M, int N, int K,
    int ldA, int ldB, long sA, long sB, long sC, int ldC,
    char* smem, int z)
{
    const int t = threadIdx.x;
    const int w = t >> 6, l = t & 63;
    const int q = l >> 4, r16 = l & 15;
    const int wr = w >> 2, wc = w & 3;   // 2M x 4N waves
    const int nbm = M >> 8, nbn = N >> 8;
    const int nwg = nbm * nbn;
    int f = blockIdx.x;
    {   // bijective XCD swizzle (m204)
        const int q8 = nwg >> 3, r8 = nwg & 7;
        const int xcd = f & 7, rank = f >> 3;
        f = (xcd < r8 ? xcd * (q8 + 1) : r8 * (q8 + 1) + (xcd - r8) * q8) + rank;
    }
    long m0, n0;
    if (ORDER == 0) { m0 = (long)(f % nbm) << 8; n0 = (long)(f / nbm) << 8; }
    else            { n0 = (long)(f % nbn) << 8; m0 = (long)(f / nbn) << 8; }
    const char* Azb = (const char*)(A + (long)z * sA);
    const char* Bzb = (const char*)(Bt + (long)z * sB);

    // staging addresses (advance +128B per K-tile); inverse-swizzled source
    const char* pa[4];
    const char* pb[4];
    int ldsd[4];
    #pragma unroll
    for (int i = 0; i < 4; ++i) {
        const int d = i * 8192 + t * 16;
        const int row = d >> 7;
        const int cb = (d & 127) ^ ((row & 7) << 4);
        pa[i] = Azb + ((m0 + row) * (long)ldA) * 2 + cb;
        pb[i] = Bzb + ((n0 + row) * (long)ldB) * 2 + cb;
        ldsd[i] = d;
    }
    auto stage = [&](int slot) {
        char* base = smem + slot * 65536;
        #pragma unroll
        for (int i = 0; i < 4; ++i) GLD16(pa[i], base + ldsd[i]);
        #pragma unroll
        for (int i = 0; i < 4; ++i) GLD16(pb[i], base + 32768 + ldsd[i]);
        #pragma unroll
        for (int i = 0; i < 4; ++i) { pa[i] += 128; pb[i] += 128; }
    };

    // hoisted LDS read offsets
    const int mask = (l & 7) << 4;
    const int cx  = (q << 4) ^ mask;
    int offA[2], offB[2];
    offA[0] = (wr * 128 + r16) * 128 + cx;
    offA[1] = (wr * 128 + r16) * 128 + (cx ^ 64);
    offB[0] = 32768 + (wc * 64 + r16) * 128 + cx;
    offB[1] = 32768 + (wc * 64 + r16) * 128 + (cx ^ 64);

#define DSA(dst, bs_, mih, kk) do { const char* p_ = (bs_) + offA[kk] + (mih) * 8192; \
    dst[0] = *(const bf16x8*)(p_);        dst[1] = *(const bf16x8*)(p_ + 2048); \
    dst[2] = *(const bf16x8*)(p_ + 4096); dst[3] = *(const bf16x8*)(p_ + 6144); } while (0)
#define DSB(dst, bs_, kk) do { const char* p_ = (bs_) + offB[kk]; \
    dst[0] = *(const bf16x8*)(p_);        dst[1] = *(const bf16x8*)(p_ + 2048); \
    dst[2] = *(const bf16x8*)(p_ + 4096); dst[3] = *(const bf16x8*)(p_ + 6144); } while (0)
#define MM16(ar, br, mih) do { __builtin_amdgcn_s_setprio(1); \
    _Pragma("unroll") for (int j = 0; j < 4; ++j) \
    _Pragma("unroll") for (int ni = 0; ni < 4; ++ni) \
        acc[(mih) * 4 + j][ni] = __builtin_amdgcn_mfma_f32_16x16x32_bf16( \
            ar[j], br[ni], acc[(mih) * 4 + j][ni], 0, 0, 0); \
    __builtin_amdgcn_s_setprio(0); SBAR(); } while (0)

    f32x4 acc[8][4] = {};
    const int nK = K >> 6;
    stage(0);

    for (int tk = 0; tk < nK; ++tk) {
        const int s = tk & 1;
        asm volatile("s_waitcnt vmcnt(0)" ::: "memory");
        SBAR();
        __builtin_amdgcn_s_barrier();
        SBAR();
        if (tk + 1 < nK) stage(s ^ 1);
        SBAR();

        const char* bs_ = smem + s * 65536;
        bf16x8 aP[4], bP[4], aQ[4], bQ[4];
        DSB(bP, bs_, 0); DSA(aP, bs_, 0, 0);
        DSA(aQ, bs_, 1, 0);
        WAIT_LGKM(4);  MM16(aP, bP, 0);
        DSB(bQ, bs_, 1); DSA(aP, bs_, 0, 1);
        WAIT_LGKM(8);  MM16(aQ, bP, 1);
        DSA(aQ, bs_, 1, 1);
        WAIT_LGKM(4);  MM16(aP, bQ, 0);
        WAIT_LGKM(0);  MM16(aQ, bQ, 1);
        asm volatile("s_waitcnt lgkmcnt(0)" ::: "memory");
        SBAR();
        __builtin_amdgcn_s_barrier();
        SBAR();
    }

    const float alpha = (OUT_MODE >= 3) ? alphap[0] : 0.0f;
    #pragma unroll
    for (int mi = 0; mi < 8; ++mi) {
        #pragma unroll
        for (int ni = 0; ni < 4; ++ni) {
            #pragma unroll
            for (int r = 0; r < 4; ++r) {
                const long row = m0 + wr * 128 + mi * 16 + q * 4 + r;
                const long col = n0 + wc * 64 + ni * 16 + r16;
                float vv = acc[mi][ni][r];
                if (BIAS_MODE == 1) vv += bias[col];
                if (BIAS_MODE == 2) vv += bias[row];
                if (OUT_MODE == 0) {
                    ((__hip_bfloat16*)outp)[(long)z * sC + row * ldC + col] = __float2bfloat16(vv);
                } else if (OUT_MODE == 1) {
                    ((float*)outp)[(long)z * sC + row * ldC + col] = vv;
                } else if (OUT_MODE == 2) {
                    const long addr = (col >> 8) * (long)(kC * kHW) + row * kHW + (col & 255);
                    ((__hip_bfloat16*)outp)[addr] = __float2bfloat16(vv);
                } else if (OUT_MODE == 3) {
                    const long addr = (col >> 8) * (long)(kC * kHW) + row * kHW + (col & 255);
                    ((float*)outp)[addr] = alpha * vv + resid[addr];
                } else {  // OUT_MODE == 4: PV epilogue
                    const long addr = (long)z * (kC * kHW) + row * kHW + col;
                    const float term = vv + aux1[row] * aux2[(long)z * 256 + col] + bias[row];
                    ((float*)outp)[addr] = alpha * term + resid[addr];
                }
            }
        }
    }
#undef DSA
#undef DSB
#undef MM16
}

template<int OUT_MODE, int BIAS_MODE, int ORDER>
__global__ __launch_bounds__(512, 2) void gemm_q(
    const __hip_bfloat16* __restrict__ A,
    const __hip_bfloat16* __restrict__ Bt,
    void* __restrict__ outp,
    const float* __restrict__ bias,
    const float* __restrict__ resid,
    const float* __restrict__ alphap,
    const float* __restrict__ aux1,
    const float* __restrict__ aux2,
    int M, int N, int K,
    int ldA, int ldB, long sA, long sB, long sC, int ldC)
{
    extern __shared__ char smem[];
    gemm_body<OUT_MODE, BIAS_MODE, ORDER>(A, Bt, outp, bias, resid, alphap,
        aux1, aux2, M, N, K, ldA, ldB, sA, sB, sC, ldC, smem, blockIdx.z);
}

// Dual dispatch: z=0 -> uT = xT*G^T + w1; z=1 -> rv conv = W2*xT^T.
// 640 blocks x 2 z = 1280 = exactly 5 full block-waves (no tail).
__global__ __launch_bounds__(512, 2) void gemm_dual(
    const __hip_bfloat16* __restrict__ xT,
    const __hip_bfloat16* __restrict__ G,
    __hip_bfloat16* __restrict__ uT,
    const float* __restrict__ w1,
    const __hip_bfloat16* __restrict__ W2,
    __hip_bfloat16* __restrict__ rv)
{
    extern __shared__ char smem[];
    if (blockIdx.z == 0) {
        gemm_body<0, 1, 1>(xT, G, uT, w1, nullptr, nullptr, nullptr, nullptr,
            32768, 1280, 1280, 1280, 1280, 0, 0, 0, 1280, smem, 0);
    } else {
        gemm_body<2, 0, 0>(W2, xT, rv, nullptr, nullptr, nullptr, nullptr, nullptr,
            1280, 32768, 1280, 1280, 1280, 0, 0, 0, 0, smem, 0);
    }
}

// K-split weight-product GEMM: z = pair*2 + khalf (pair 0: G=WkT*WqT^T,
// pair 1: W2=Wrb*WvT^T), K=640 each, f32 partials Gp[z]. 100 blocks total.
__global__ __launch_bounds__(512, 2) void gemm_gsplit(
    const __hip_bfloat16* __restrict__ WkT,
    const __hip_bfloat16* __restrict__ WqT,
    const __hip_bfloat16* __restrict__ Wrb,
    const __hip_bfloat16* __restrict__ WvT,
    float* __restrict__ Gp)
{
    extern __shared__ char smem[];
    const int zz = blockIdx.z;
    const int pair = zz >> 1, ks = zz & 1;
    const __hip_bfloat16* A  = (pair ? Wrb : WkT) + ks * 640;
    const __hip_bfloat16* Bt = (pair ? WvT : WqT) + ks * 640;
    gemm_body<1, 0, 0>(A, Bt, Gp, nullptr, nullptr, nullptr, nullptr, nullptr,
        1280, 1280, 640, 1280, 1280, 0, 0, 1638400, 1280, smem, zz);
}

// G = bf16(Gp0+Gp1), W2 = bf16(Gp2+Gp3); 1638400 elems, float4 per thread
__global__ __launch_bounds__(256) void reduce_gw(
    const float* __restrict__ Gp,
    __hip_bfloat16* __restrict__ G, __hip_bfloat16* __restrict__ W2)
{
    const long i = ((long)blockIdx.x * 256 + threadIdx.x) * 4;
    const float4 a = *reinterpret_cast<const float4*>(Gp + i);
    const float4 b = *reinterpret_cast<const float4*>(Gp + 1638400 + i);
    G[i + 0] = __float2bfloat16(a.x + b.x);
    G[i + 1] = __float2bfloat16(a.y + b.y);
    G[i + 2] = __float2bfloat16(a.z + b.z);
    G[i + 3] = __float2bfloat16(a.w + b.w);
    const float4 c = *reinterpret_cast<const float4*>(Gp + 2L * 1638400 + i);
    const float4 d = *reinterpret_cast<const float4*>(Gp + 3L * 1638400 + i);
    W2[i + 0] = __float2bfloat16(c.x + d.x);
    W2[i + 1] = __float2bfloat16(c.y + d.y);
    W2[i + 2] = __float2bfloat16(c.z + d.z);
    W2[i + 3] = __float2bfloat16(c.w + d.w);
}

// x (B, C, HW) f32 -> xT (B*HW, C) bf16; fused partial c2s[p] += sum_c x[c][p]*w2[c]
__global__ __launch_bounds__(256) void transpose_x(
    const float* __restrict__ x, __hip_bfloat16* __restrict__ xT,
    const float* __restrict__ w2, float* __restrict__ c2s)
{
    __shared__ float tile[64][65];
    __shared__ float red[4][64];
    const int b = blockIdx.z;
    const int c0 = blockIdx.x * 64;
    const int p0 = blockIdx.y * 64;
    const int tj = threadIdx.x & 63;
    const int ti = threadIdx.x >> 6;
    const float* xb = x + ((long)b * kC + c0) * kHW + p0;
    #pragma unroll
    for (int i = 0; i < 16; ++i) {
        const int c = i * 4 + ti;
        tile[c][tj] = xb[(long)c * kHW + tj];
    }
    __syncthreads();
    __hip_bfloat16* o = xT + ((long)(b * kHW + p0)) * kC + c0;
    #pragma unroll
    for (int i = 0; i < 16; ++i) {
        const int p = i * 4 + ti;
        o[(long)p * kC + tj] = __float2bfloat16(tile[tj][p]);
    }
    float s = 0.0f;
    #pragma unroll
    for (int j = 0; j < 16; ++j)
        s += tile[ti * 16 + j][tj] * w2[c0 + ti * 16 + j];
    red[ti][tj] = s;
    __syncthreads();
    if (ti == 0)
        atomicAdd(&c2s[b * 256 + p0 + tj], red[0][tj] + red[1][tj] + red[2][tj] + red[3][tj]);
}

// z<3: W -> WT bf16 transposed; z==3: Wr -> Wrb bf16 (plain convert)
__global__ __launch_bounds__(256) void transpose_w4(
    const float* __restrict__ Wk, __hip_bfloat16* __restrict__ WkT,
    const float* __restrict__ Wq, __hip_bfloat16* __restrict__ WqT,
    const float* __restrict__ Wv, __hip_bfloat16* __restrict__ WvT,
    const float* __restrict__ Wr, __hip_bfloat16* __restrict__ Wrb)
{
    const int zz = blockIdx.z;
    const float* W = (zz == 0) ? Wk : (zz == 1) ? Wq : (zz == 2) ? Wv : Wr;
    __hip_bfloat16* WT = (zz == 0) ? WkT : (zz == 1) ? WqT : (zz == 2) ? WvT : Wrb;
    __shared__ float tile[64][65];
    const int o0 = blockIdx.x * 64;
    const int c0 = blockIdx.y * 64;
    const int tj = threadIdx.x & 63;
    const int ti = threadIdx.x >> 6;
    #pragma unroll
    for (int i = 0; i < 16; ++i) {
        const int o = i * 4 + ti;
        tile[o][tj] = W[(long)(o0 + o) * kC + c0 + tj];
    }
    __syncthreads();
    if (zz < 3) {
        #pragma unroll
        for (int i = 0; i < 16; ++i) {
            const int c = i * 4 + ti;
            WT[(long)(c0 + c) * kC + o0 + tj] = __float2bfloat16(tile[tj][c]);
        }
    } else {
        #pragma unroll
        for (int i = 0; i < 16; ++i) {
            const int o = i * 4 + ti;
            WT[(long)(o0 + o) * kC + c0 + tj] = __float2bfloat16(tile[o][tj]);
        }
    }
}

__global__ __launch_bounds__(256) void zero_f32(float* __restrict__ p)
{
    reinterpret_cast<float4*>(p)[blockIdx.x * 256 + threadIdx.x] =
        make_float4(0.f, 0.f, 0.f, 0.f);
}

// y=0: w1[c] = sum_o Wk[o][c]*bq[o];  y=1: w2[c] = sum_o Wq[o][c]*bk[o]
__global__ __launch_bounds__(256) void gemv_col(
    const float* __restrict__ Wk, const float* __restrict__ bq,
    const float* __restrict__ Wq, const float* __restrict__ bk,
    float* __restrict__ w1, float* __restrict__ w2)
{
    const float* W = blockIdx.y ? Wq : Wk;
    const float* v = blockIdx.y ? bk : bq;
    float* out = blockIdx.y ? w2 : w1;
    const int lj = threadIdx.x & 63;
    const int wid = threadIdx.x >> 6;
    const int c = blockIdx.x * 64 + lj;
    __shared__ float red[4][64];
    float s = 0.0f;
    for (int o = wid * 320; o < (wid + 1) * 320; ++o)
        s += W[(long)o * kC + c] * v[o];
    red[wid][lj] = s;
    __syncthreads();
    if (wid == 0) out[c] = red[0][lj] + red[1][lj] + red[2][lj] + red[3][lj];
}

// wrbv[o] = sum_j Wr[o][j]*bv[j]
__global__ __launch_bounds__(256) void gemv_row(
    const float* __restrict__ Wr, const float* __restrict__ bv, float* __restrict__ out)
{
    const int wid = threadIdx.x >> 6, lj = threadIdx.x & 63;
    const int o = blockIdx.x * 4 + wid;
    float s = 0.0f;
    #pragma unroll
    for (int j = 0; j < 20; ++j)
        s += Wr[(long)o * kC + j * 64 + lj] * bv[j * 64 + lj];
    #pragma unroll
    for (int off = 32; off > 0; off >>= 1) s += __shfl_down(s, off);
    if (lj == 0) out[o] = s;
}

// c0 = dot(bk, bq)
__global__ __launch_bounds__(256) void dot_k(
    const float* __restrict__ a, const float* __restrict__ b, float* __restrict__ out)
{
    __shared__ float red[256];
    const int t_ = threadIdx.x;
    float s = 0.0f;
    for (int j = t_; j < kC; j += 256) s += a[j] * b[j];
    red[t_] = s; __syncthreads();
    for (int off = 128; off > 0; off >>= 1) {
        if (t_ < off) red[t_] += red[t_ + off];
        __syncthreads();
    }
    if (t_ == 0) out[0] = red[0];
}

// rs[p] = sum_m attn[p*256 + m]
__global__ __launch_bounds__(256) void rowsum_attn(
    const __hip_bfloat16* __restrict__ attn, float* __restrict__ rs)
{
    const int wid = threadIdx.x >> 6, lj = threadIdx.x & 63;
    const long p = (long)blockIdx.x * 4 + wid;
    const ushort4 v = *(const ushort4*)((const char*)attn + p * 512 + lj * 8);
    float s = bf2f(v.x) + bf2f(v.y) + bf2f(v.z) + bf2f(v.w);
    #pragma unroll
    for (int off = 32; off > 0; off >>= 1) s += __shfl_down(s, off);
    if (lj == 0) rs[p] = s;
}

// softmax over BATCH axis with rank-1 corrections
__global__ __launch_bounds__(256) void softmax_batch(
    const float* __restrict__ sc, __hip_bfloat16* __restrict__ attn,
    const float* __restrict__ c2s, const float* __restrict__ c0p)
{
    const int pos = blockIdx.x * 256 + threadIdx.x;
    const int mcol = pos & 255;
    const float c0v = c0p[0];
    float m = -3.0e38f, s = 0.0f;
    for (int b = 0; b < kB; ++b) {
        const float v = sc[(long)b * 65536 + pos] + c2s[b * 256 + mcol] + c0v;
        const float mn = fmaxf(m, v);
        s = s * __expf(m - mn) + __expf(v - mn);
        m = mn;
    }
    const float rinv = 1.0f / s;
    for (int b = 0; b < kB; ++b) {
        const float v = sc[(long)b * 65536 + pos] + c2s[b * 256 + mcol] + c0v;
        attn[(long)b * 65536 + pos] = __float2bfloat16(__expf(v - m) * rinv);
    }
}

extern "C" void kernel_launch(void* const* d_in, const int* in_sizes, int n_in,
                              void* d_out, int out_size, void* d_ws, size_t ws_size,
                              hipStream_t stream)
{
    const float* x  = (const float*)d_in[0];
    const float* Wk = (const float*)d_in[1];
    const float* bk = (const float*)d_in[2];
    const float* Wq = (const float*)d_in[3];
    const float* bq = (const float*)d_in[4];
    const float* Wv = (const float*)d_in[5];
    const float* bv = (const float*)d_in[6];
    const float* Wr = (const float*)d_in[7];
    const float* br = (const float*)d_in[8];
    const float* al = (const float*)d_in[9];

    char* ws = (char*)d_ws;
    __hip_bfloat16* xT   = (__hip_bfloat16*)(ws);               // (32768,1280) 83.9MB
    __hip_bfloat16* uT   = (__hip_bfloat16*)(ws + 83886080L);   // 83.9MB
    __hip_bfloat16* rv   = (__hip_bfloat16*)(ws + 167772160L);  // conv 83.9MB
    float*          sc   = (float*)(ws + 251658240L);           // 33.5MB
    __hip_bfloat16* attn = (__hip_bfloat16*)(ws + 285212672L);  // 16.8MB
    __hip_bfloat16* WkT  = (__hip_bfloat16*)(ws + 301989888L);  // 3.28MB each
    __hip_bfloat16* Wrb  = (__hip_bfloat16*)(ws + 305266688L);
    __hip_bfloat16* WqT  = (__hip_bfloat16*)(ws + 308543488L);
    __hip_bfloat16* WvT  = (__hip_bfloat16*)(ws + 311820288L);
    __hip_bfloat16* G    = (__hip_bfloat16*)(ws + 315097088L);
    __hip_bfloat16* W2   = (__hip_bfloat16*)(ws + 318373888L);
    float*          w1   = (float*)(ws + 321650688L);
    float*          w2v  = (float*)(ws + 321655808L);
    float*          wrbv = (float*)(ws + 321660928L);
    float*          c0b  = (float*)(ws + 321666048L);
    float*          c2s  = (float*)(ws + 321666560L);           // 32768 f32
    float*          rs   = (float*)(ws + 321797632L);           // 32768 f32
    float*          Gp   = (float*)(ws + 321928704L);           // 4x 6.55MB = 26.2MB

    const int SMEM = 131072;
    hipFuncSetAttribute((const void*)gemm_q<1,0,0>, hipFuncAttributeMaxDynamicSharedMemorySize, SMEM);
    hipFuncSetAttribute((const void*)gemm_q<4,0,0>, hipFuncAttributeMaxDynamicSharedMemorySize, SMEM);
    hipFuncSetAttribute((const void*)gemm_dual,     hipFuncAttributeMaxDynamicSharedMemorySize, SMEM);
    hipFuncSetAttribute((const void*)gemm_gsplit,   hipFuncAttributeMaxDynamicSharedMemorySize, SMEM);

    // weight preprocessing
    transpose_w4<<<dim3(20, 20, 4), 256, 0, stream>>>(Wk, WkT, Wq, WqT, Wv, WvT, Wr, Wrb);
    gemv_col<<<dim3(20, 2), 256, 0, stream>>>(Wk, bq, Wq, bk, w1, w2v);
    gemv_row<<<320, 256, 0, stream>>>(Wr, bv, wrbv);
    dot_k<<<1, 256, 0, stream>>>(bk, bq, c0b);
    zero_f32<<<32, 256, 0, stream>>>(c2s);
    transpose_x<<<dim3(20, 4, 128), 256, 0, stream>>>(x, xT, w2v, c2s);

    // G = WkT*WqT^T, W2 = Wrb*WvT^T via K-split x2 (100 blocks), then reduce
    gemm_gsplit<<<dim3(25, 1, 4), 512, SMEM, stream>>>(WkT, WqT, Wrb, WvT, Gp);
    reduce_gw<<<1600, 256, 0, stream>>>(Gp, G, W2);
    // dual: uT = xT*G^T + w1  |  rv = W2*x (conv); 1280 blocks = 5 full waves
    gemm_dual<<<dim3(640, 1, 2), 512, SMEM, stream>>>(xT, G, uT, w1, W2, rv);
    // sc[b] (256,256) f32 = xT[b] * uT[b]^T
    gemm_q<1, 0, 0><<<dim3(1, 1, 128), 512, SMEM, stream>>>(xT, uT, sc,
        nullptr, nullptr, nullptr, nullptr, nullptr,
        256, 256, 1280, 1280, 1280, 327680, 327680, 65536, 256);
    softmax_batch<<<256, 256, 0, stream>>>(sc, attn, c2s, c0b);
    rowsum_attn<<<8192, 256, 0, stream>>>(attn, rs);
    // out[b][c][n] = alpha*(sum_m rv[b][c][m]*attn[b][n][m] + wrbv[c]*rs[b,n] + br[c]) + x
    gemm_q<4, 0, 0><<<dim3(5, 1, 128), 512, SMEM, stream>>>(rv, attn, d_out,
        br, x, al, wrbv, rs,
        1280, 256, 256, 256, 256, 327680, 65536, 0, 0);
}